// Round 1
// baseline (257.010 us; speedup 1.0000x reference)
//
#include <hip/hip_runtime.h>

constexpr int S_ = 4096;
constexpr int D_ = 512;
constexpr int NJC = 4;            // j-chunks for parallelism
constexpr int JC = S_ / NJC;      // 1024

using f32x4 = __attribute__((ext_vector_type(4))) float;
using s16x8 = __attribute__((ext_vector_type(8))) short;
using u16x4 = __attribute__((ext_vector_type(4))) unsigned short;
using u16x8 = __attribute__((ext_vector_type(8))) unsigned short;

__device__ __forceinline__ unsigned short f2bf(float f) {
    union { float f; unsigned u; } v; v.f = f;
    unsigned r = v.u + 0x7FFFu + ((v.u >> 16) & 1u);
    return (unsigned short)(r >> 16);
}

// Y[M=4096][N=512] = X[M][512] @ W[N][512]^T
// OUT_MODE: 0 = bf16 row-major, 1 = bf16 transposed ([N][S_]), 2 = fp32 row-major
template<bool IN_BF16, int OUT_MODE>
__global__ __launch_bounds__(256) void proj_kernel(const void* __restrict__ Xv,
                                                   const float* __restrict__ W,
                                                   void* __restrict__ Yv) {
    constexpr int BM = 128, BN = 64, BK = 64;
    __shared__ unsigned short Xs[BM][BK + 8];   // row = 144B (16B-aligned, bank-rotated)
    __shared__ unsigned short Ws_[BN][BK + 8];
    const int m0 = blockIdx.x * BM;
    const int n0 = blockIdx.y * BN;
    const int tid = threadIdx.x;
    const int lane = tid & 63, w = tid >> 6;
    const int wi = w >> 1, wj = w & 1;          // wave tile: 64 rows x 32 cols
    const int lr = lane & 15, lg = lane >> 4;

    f32x4 acc[4][2] = {};

    for (int kt = 0; kt < D_ / BK; ++kt) {
        const int k0 = kt * BK;
        __syncthreads();
        if (IN_BF16) {
            const unsigned short* X = (const unsigned short*)Xv;
#pragma unroll
            for (int r = 0; r < 4; ++r) {
                int idx = tid + r * 256;           // 1024 chunks of 8
                int row = idx >> 3, c8 = idx & 7;
                u16x8 vv = *(const u16x8*)(X + (size_t)(m0 + row) * D_ + k0 + c8 * 8);
                *(u16x8*)&Xs[row][c8 * 8] = vv;
            }
        } else {
            const float* X = (const float*)Xv;
#pragma unroll
            for (int r = 0; r < 8; ++r) {
                int idx = tid + r * 256;           // 2048 float4
                int row = idx >> 4, c4 = idx & 15;
                f32x4 vv = *(const f32x4*)(X + (size_t)(m0 + row) * D_ + k0 + c4 * 4);
                u16x4 o;
#pragma unroll
                for (int t = 0; t < 4; ++t) o[t] = f2bf(vv[t]);
                *(u16x4*)&Xs[row][c4 * 4] = o;
            }
        }
#pragma unroll
        for (int r = 0; r < 4; ++r) {
            int idx = tid + r * 256;               // 1024 float4
            int row = idx >> 4, c4 = idx & 15;
            f32x4 vv = *(const f32x4*)(W + (size_t)(n0 + row) * D_ + k0 + c4 * 4);
            u16x4 o;
#pragma unroll
            for (int t = 0; t < 4; ++t) o[t] = f2bf(vv[t]);
            *(u16x4*)&Ws_[row][c4 * 4] = o;
        }
        __syncthreads();
#pragma unroll
        for (int ks = 0; ks < 2; ++ks) {
            s16x8 a[4], b[2];
#pragma unroll
            for (int mf = 0; mf < 4; ++mf)
                a[mf] = *(const s16x8*)&Xs[wi * 64 + mf * 16 + lr][ks * 32 + lg * 8];
#pragma unroll
            for (int nf = 0; nf < 2; ++nf)
                b[nf] = *(const s16x8*)&Ws_[wj * 32 + nf * 16 + lr][ks * 32 + lg * 8];
#pragma unroll
            for (int mf = 0; mf < 4; ++mf)
#pragma unroll
                for (int nf = 0; nf < 2; ++nf)
                    acc[mf][nf] = __builtin_amdgcn_mfma_f32_16x16x32_bf16(a[mf], b[nf], acc[mf][nf], 0, 0, 0);
        }
    }

    if (OUT_MODE == 1) {
        // transpose through LDS, then coalesced 16B stores of V^T rows
        __syncthreads();
        unsigned short* T = &Xs[0][0] + w * 2304;   // per-wave [32][72]
#pragma unroll
        for (int mf = 0; mf < 4; ++mf)
#pragma unroll
            for (int nf = 0; nf < 2; ++nf)
#pragma unroll
                for (int r = 0; r < 4; ++r) {
                    int n_loc = nf * 16 + lr;
                    int i_loc = mf * 16 + lg * 4 + r;
                    T[n_loc * 72 + i_loc] = f2bf(acc[mf][nf][r]);
                }
        __syncthreads();  // wave-private region, but cheap safety for LDS data visibility
        unsigned short* Y = (unsigned short*)Yv;
#pragma unroll
        for (int rr = 0; rr < 4; ++rr) {
            int chunk = lane + rr * 64;            // 256 chunks of 8
            int n_loc = chunk >> 3, c8 = chunk & 7;
            u16x8 vv = *(const u16x8*)&T[n_loc * 72 + c8 * 8];
            *(u16x8*)(Y + (size_t)(n0 + wj * 32 + n_loc) * S_ + m0 + wi * 64 + c8 * 8) = vv;
        }
    } else {
#pragma unroll
        for (int mf = 0; mf < 4; ++mf)
#pragma unroll
            for (int nf = 0; nf < 2; ++nf)
#pragma unroll
                for (int r = 0; r < 4; ++r) {
                    int i = m0 + wi * 64 + mf * 16 + lg * 4 + r;
                    int n = n0 + wj * 32 + nf * 16 + lr;
                    float val = acc[mf][nf][r];
                    if (OUT_MODE == 0) ((unsigned short*)Yv)[(size_t)i * D_ + n] = f2bf(val);
                    else                ((float*)Yv)[(size_t)i * D_ + n] = val;
                }
    }
}

// Attention with head-axis softmax. One block: 32 q-rows, one j-chunk (1024 keys).
// Per 32x32 tile: each wave computes all 8 head scores for one 16x16 quadrant
// (softmax lane-local, normalized P written to LDS), then 2 heads for PV.
__global__ __launch_bounds__(256) void attn_kernel(const unsigned short* __restrict__ Qp,
                                                   const unsigned short* __restrict__ Kp,
                                                   const unsigned short* __restrict__ VpT,
                                                   float* __restrict__ partial) {
    constexpr int BI = 32, BJ = 32;
    __shared__ unsigned short Qs[BI][520];       // 512 + 8 pad, row 1040B
    __shared__ unsigned short Es[8][BI][40];     // normalized P, [h][i][j], row 80B
    const int i0 = blockIdx.x * BI;
    const int jc = blockIdx.y;
    const int tid = threadIdx.x;
    const int lane = tid & 63, w = tid >> 6;
    const int lr = lane & 15, lg = lane >> 4;
    const int qi = (w >> 1) * 16, qj = (w & 1) * 16;   // QK quadrant of this wave

#pragma unroll
    for (int r = 0; r < 8; ++r) {                // stage Q tile 32x512 bf16
        int idx = tid + r * 256;
        int row = idx >> 6, c8 = idx & 63;
        u16x8 vv = *(const u16x8*)(Qp + (size_t)(i0 + row) * D_ + c8 * 8);
        *(u16x8*)&Qs[row][c8 * 8] = vv;
    }

    f32x4 out[2][2][4] = {};                      // [head][ifrag][dfrag]

    for (int t = 0; t < JC / BJ; ++t) {
        const int j0 = jc * JC + t * BJ;
        __syncthreads();                          // P of prev tile consumed; Qs staged (t=0)

        // ---- QK^T for quadrant (qi,qj), all 8 heads ----
        f32x4 sfrag[8];
#pragma unroll
        for (int h = 0; h < 8; ++h) {
            f32x4 sf = {0.f, 0.f, 0.f, 0.f};
#pragma unroll
            for (int ks = 0; ks < 2; ++ks) {
                s16x8 a = *(const s16x8*)&Qs[qi + lr][h * 64 + ks * 32 + lg * 8];
                s16x8 b = *(const s16x8*)(Kp + (size_t)(j0 + qj + lr) * D_ + h * 64 + ks * 32 + lg * 8);
                sf = __builtin_amdgcn_mfma_f32_16x16x32_bf16(a, b, sf, 0, 0, 0);
            }
            sfrag[h] = sf;
        }
        // ---- head-softmax, lane-local, write normalized P (bf16) ----
#pragma unroll
        for (int r = 0; r < 4; ++r) {
            float e[8], den = 0.f;
#pragma unroll
            for (int h = 0; h < 8; ++h) { e[h] = __expf(sfrag[h][r] * 0.125f); den += e[h]; }
            float rd = __builtin_amdgcn_rcpf(den);
            int i_loc = qi + lg * 4 + r, j_loc = qj + lr;
#pragma unroll
            for (int h = 0; h < 8; ++h)
                Es[h][i_loc][j_loc] = f2bf(e[h] * rd);
        }
        __syncthreads();

        // ---- PV: this wave owns heads 2w, 2w+1; k-dim = 32 j's (one MFMA step) ----
#pragma unroll
        for (int hh = 0; hh < 2; ++hh) {
            int h = 2 * w + hh;
            s16x8 b[4];
#pragma unroll
            for (int df = 0; df < 4; ++df)
                b[df] = *(const s16x8*)(VpT + (size_t)(h * 64 + df * 16 + lr) * S_ + j0 + lg * 8);
#pragma unroll
            for (int mf = 0; mf < 2; ++mf) {
                s16x8 a = *(const s16x8*)&Es[h][mf * 16 + lr][lg * 8];
#pragma unroll
                for (int df = 0; df < 4; ++df)
                    out[hh][mf][df] = __builtin_amdgcn_mfma_f32_16x16x32_bf16(a, b[df], out[hh][mf][df], 0, 0, 0);
            }
        }
    }

    float* P = partial + (size_t)jc * S_ * D_;
#pragma unroll
    for (int hh = 0; hh < 2; ++hh) {
        int h = 2 * w + hh;
#pragma unroll
        for (int mf = 0; mf < 2; ++mf)
#pragma unroll
            for (int df = 0; df < 4; ++df)
#pragma unroll
                for (int r = 0; r < 4; ++r) {
                    int i = i0 + mf * 16 + lg * 4 + r;
                    int d = h * 64 + df * 16 + lr;
                    P[(size_t)i * D_ + d] = out[hh][mf][df][r];
                }
    }
}

__global__ __launch_bounds__(256) void reduce4_kernel(const float* __restrict__ partial,
                                                      unsigned short* __restrict__ outp) {
    size_t base = ((size_t)blockIdx.x * 256 + threadIdx.x) * 4;
    f32x4 s = *(const f32x4*)(partial + base);
#pragma unroll
    for (int c = 1; c < NJC; ++c) {
        f32x4 vv = *(const f32x4*)(partial + (size_t)c * S_ * D_ + base);
        s += vv;
    }
    u16x4 o;
#pragma unroll
    for (int t = 0; t < 4; ++t) o[t] = f2bf(s[t]);
    *(u16x4*)(outp + base) = o;
}

extern "C" void kernel_launch(void* const* d_in, const int* in_sizes, int n_in,
                              void* d_out, int out_size, void* d_ws, size_t ws_size,
                              hipStream_t stream) {
    const float* q  = (const float*)d_in[0];
    const float* k  = (const float*)d_in[1];
    const float* v  = (const float*)d_in[2];
    const float* Wq = (const float*)d_in[3];
    const float* Wk = (const float*)d_in[4];
    const float* Wv = (const float*)d_in[5];
    const float* Wo = (const float*)d_in[6];

    char* ws = (char*)d_ws;
    unsigned short* Qp  = (unsigned short*)(ws);                    // 4 MB bf16 [S][D]
    unsigned short* Kp  = (unsigned short*)(ws + (4u  << 20));      // 4 MB bf16 [S][D]
    unsigned short* VpT = (unsigned short*)(ws + (8u  << 20));      // 4 MB bf16 [D][S]
    float*          part= (float*)        (ws + (12u << 20));       // 32 MB fp32 [NJC][S][D]
    unsigned short* ao  = (unsigned short*)(ws + (44u << 20));      // 4 MB bf16 [S][D]

    dim3 pb(256);
    dim3 pg(S_ / 128, D_ / 64);
    proj_kernel<false, 0><<<pg, pb, 0, stream>>>(q, Wq, Qp);
    proj_kernel<false, 0><<<pg, pb, 0, stream>>>(k, Wk, Kp);
    proj_kernel<false, 1><<<pg, pb, 0, stream>>>(v, Wv, VpT);
    attn_kernel<<<dim3(S_ / 32, NJC), pb, 0, stream>>>(Qp, Kp, VpT, part);
    reduce4_kernel<<<dim3(S_ * D_ / 1024), pb, 0, stream>>>(part, ao);
    proj_kernel<true, 2><<<pg, pb, 0, stream>>>(ao, Wo, (float*)d_out);
}